// Round 19
// baseline (136.307 us; speedup 1.0000x reference)
//
#include <hip/hip_runtime.h>
#include <stdint.h>

#define BATCH 2
#define SEQ   2048
#define EMB   1024
#define NH    16
#define HD    64
#define MROWS (BATCH*SEQ)   // 4096
#define LOG2E 1.4426950408889634f

using bf16x8 = __attribute__((ext_vector_type(8))) short;
using f32x4  = __attribute__((ext_vector_type(4))) float;
using f32x16 = __attribute__((ext_vector_type(16))) float;

__device__ __forceinline__ unsigned short f2bf(float f) {
  __bf16 b = (__bf16)f;                       // RNE fptrunc
  return __builtin_bit_cast(unsigned short, b);
}

__device__ __forceinline__ float bf2f(unsigned short u) {
  return __builtin_bit_cast(float, (unsigned int)u << 16);
}

__device__ __forceinline__ unsigned int cvtpk_bf16(float lo, float hi) {
  unsigned int w;
  asm("v_cvt_pk_bf16_f32 %0, %1, %2" : "=v"(w) : "v"(lo), "v"(hi));
  return w;
}

// 2^x in one v_exp_f32 (compiler-modeled). Inputs pre-scaled to exp2 domain.
#if __has_builtin(__builtin_amdgcn_exp2f)
__device__ __forceinline__ float fast_exp2(float x) { return __builtin_amdgcn_exp2f(x); }
#else
__device__ __forceinline__ float fast_exp2(float x) {
  float r;
  asm("v_exp_f32 %0, %1\n\ts_nop 1" : "=v"(r) : "v"(x));
  return r;
}
#endif

// cross-32 half exchange: a' = [a_lo, b_lo], b' = [a_hi, b_hi]. VALU.
__device__ __forceinline__ void swap32(unsigned int& a, unsigned int& b, int hi) {
#if __has_builtin(__builtin_amdgcn_permlane32_swap)
  (void)hi;
  typedef unsigned int u32x2_t __attribute__((ext_vector_type(2)));
  u32x2_t r = __builtin_amdgcn_permlane32_swap(a, b, false, false);
  a = r[0]; b = r[1];
#else
  const unsigned int ca = __shfl_xor(a, 32), cb = __shfl_xor(b, 32);
  const unsigned int na = hi ? cb : a;
  const unsigned int nb = hi ? b : ca;
  a = na; b = nb;
#endif
}

__device__ __forceinline__ float xadd32(float x, int hi) {
  unsigned int a = __builtin_bit_cast(unsigned int, x), b = a;
  swap32(a, b, hi);
  return __builtin_bit_cast(float, a) + __builtin_bit_cast(float, b);
}

__device__ __forceinline__ void async_load16(const void* g, void* l) {
  __builtin_amdgcn_global_load_lds(
      (__attribute__((address_space(1))) void*)g,
      (__attribute__((address_space(3))) void*)l,
      16, 0, 0);
}

// ---------------- merged prep: convert x, convert y, transpose weights ------
__global__ __launch_bounds__(256) void prep_kernel(
    const float* __restrict__ x, const float* __restrict__ y,
    const float* __restrict__ Wq, const float* __restrict__ Wk,
    const float* __restrict__ Wv, const float* __restrict__ Wo,
    unsigned short* __restrict__ xb, unsigned short* __restrict__ yb,
    unsigned short* __restrict__ WtAll) {
  __shared__ unsigned short tile[64][65];
  const int lin = blockIdx.x;
  if (lin < 8192) {
    const float* in = (lin < 4096) ? x : y;
    unsigned short* out = (lin < 4096) ? xb : yb;
    const int i = (lin & 4095) * 256 + threadIdx.x;   // < 1048576 float4s
    const float4 v = reinterpret_cast<const float4*>(in)[i];
    ushort4 o;
    o.x = f2bf(v.x); o.y = f2bf(v.y); o.z = f2bf(v.z); o.w = f2bf(v.w);
    reinterpret_cast<ushort4*>(out)[i] = o;
    return;   // convert blocks never reach the barrier below
  }
  const int tw = lin - 8192;
  const int z = tw >> 8;                      // 0..3
  const float* W = (z == 0) ? Wq : (z == 1) ? Wk : (z == 2) ? Wv : Wo;
  unsigned short* Wt = WtAll + (size_t)z * EMB * EMB;
  const int tc = threadIdx.x & 15;
  const int tr = threadIdx.x >> 4;
  const int n0 = ((tw >> 4) & 15) * 64, k0 = (tw & 15) * 64;
#pragma unroll
  for (int rr = 0; rr < 4; ++rr) {
    const int row = rr * 16 + tr;  // k-local
    float4 v = *reinterpret_cast<const float4*>(W + (size_t)(k0 + row) * EMB + n0 + tc * 4);
    tile[tc * 4 + 0][row] = f2bf(v.x);
    tile[tc * 4 + 1][row] = f2bf(v.y);
    tile[tc * 4 + 2][row] = f2bf(v.z);
    tile[tc * 4 + 3][row] = f2bf(v.w);
  }
  __syncthreads();
#pragma unroll
  for (int rr = 0; rr < 4; ++rr) {
    const int row = rr * 16 + tr;  // n-local
    ushort4 o;
    o.x = tile[row][tc * 4 + 0];
    o.y = tile[row][tc * 4 + 1];
    o.z = tile[row][tc * 4 + 2];
    o.w = tile[row][tc * 4 + 3];
    *reinterpret_cast<ushort4*>(Wt + (size_t)(n0 + row) * EMB + k0 + tc * 4) = o;
  }
}

// ---------------- GEMM: C[m][n] = A[m][:] . Wt[n][:] + bias[n] ----------------
// BMt x 128 tile, BK=32, 4 waves. 3-buffer LDS pipeline, counted vmcnt.
// T2 both-sides XOR swizzle (r16, neutral-kept).
#define BN 128
#define BK 32
#define NKS (EMB/BK)   // 32

template <int BMt>
__global__ __launch_bounds__(256, 3) void gemm_kernel(
    const unsigned short* __restrict__ xb,
    const unsigned short* __restrict__ yb,
    const unsigned short* __restrict__ attnb,
    const unsigned short* __restrict__ WtAll,
    const float* __restrict__ bq, const float* __restrict__ bk,
    const float* __restrict__ bv, const float* __restrict__ bo,
    unsigned short* __restrict__ Qb, unsigned short* __restrict__ Kb,
    unsigned short* __restrict__ Vt, float* __restrict__ dout,
    int phase) {
  __shared__ __align__(16) unsigned short As[3][BMt * BK];
  __shared__ __align__(16) unsigned short Bs[3][BN * BK];

  const int z = blockIdx.z;
  const unsigned short* A;
  const unsigned short* Bt;
  const float* bias;
  int mode;
  if (phase == 0) {
    A    = (z == 0) ? xb : yb;
    Bt   = WtAll + (size_t)z * EMB * EMB;
    bias = (z == 0) ? bq : (z == 1) ? bk : bv;
    mode = z;                 // 0:Q 1:K(scaled by log2e) 2:V(transposed out)
  } else {
    A = attnb; Bt = WtAll + (size_t)3 * EMB * EMB; bias = bo; mode = 3;
  }

  const int tid = threadIdx.x;
  const int lane = tid & 63, wid = tid >> 6;
  constexpr int WC  = (BMt == 128) ? 2 : 4;    // wave cols
  constexpr int WCW = 128 / WC;                // cols per wave (64 or 32)
  constexpr int JN  = WCW / 16;                // j-blocks per wave (4 or 2)
  const int wr = (BMt == 128) ? (wid >> 1) : 0;
  const int wc = (BMt == 128) ? (wid & 1) : wid;
  const int l15 = lane & 15, l4 = lane >> 4;
  const int m0 = blockIdx.y * BMt, n0 = blockIdx.x * BN;

  const int crow = tid >> 2;   // 0..63
  const int cslot = tid & 3;
  const int ssw = cslot ^ ((crow >> 1) & 3);   // stage-side swizzled slot
  const int rsw = (l15 >> 1) & 3;              // read-side XOR key

  auto GSTAGE = [&](int b, int kt) {
    if constexpr (BMt == 128) {
#pragma unroll
      for (int it = 0; it < 2; ++it)
        async_load16(A + (size_t)(m0 + it * 64 + crow) * EMB + kt + ssw * 8,
                     (char*)As[b] + it * 4096 + wid * 1024);
    } else {
      async_load16(A + (size_t)(m0 + crow) * EMB + kt + ssw * 8,
                   (char*)As[b] + wid * 1024);
    }
#pragma unroll
    for (int it = 0; it < 2; ++it)
      async_load16(Bt + (size_t)(n0 + it * 64 + crow) * EMB + kt + ssw * 8,
                   (char*)Bs[b] + it * 4096 + wid * 1024);
  };

  GSTAGE(0, 0);
  GSTAGE(1, BK);

  f32x4 acc[4][JN] = {};

  int buf = 0, sb = 2;
  for (int s = 0; s < NKS; ++s) {
    __builtin_amdgcn_sched_barrier(0);
    if (s < NKS - 1) {
      if constexpr (BMt == 128) {
        asm volatile("s_waitcnt vmcnt(4)" ::: "memory");
      } else {
        asm volatile("s_waitcnt vmcnt(3)" ::: "memory");
      }
    } else {
      asm volatile("s_waitcnt vmcnt(0)" ::: "memory");
    }
    __builtin_amdgcn_s_barrier();
    __builtin_amdgcn_sched_barrier(0);

    if (s + 2 < NKS) { GSTAGE(sb, (s + 2) * BK); }

    bf16x8 af[4], bfr[JN];
#pragma unroll
    for (int i = 0; i < 4; ++i)
      af[i] = *reinterpret_cast<const bf16x8*>(
          (const char*)As[buf] + (wr * 64 + i * 16 + l15) * 64 + ((l4 ^ rsw) * 16));
#pragma unroll
    for (int j = 0; j < JN; ++j)
      bfr[j] = *reinterpret_cast<const bf16x8*>(
          (const char*)Bs[buf] + (wc * WCW + j * 16 + l15) * 64 + ((l4 ^ rsw) * 16));
#pragma unroll
    for (int i = 0; i < 4; ++i)
#pragma unroll
      for (int j = 0; j < JN; ++j)
        acc[i][j] = __builtin_amdgcn_mfma_f32_16x16x32_bf16(af[i], bfr[j], acc[i][j], 0, 0, 0);

    buf = (buf == 2) ? 0 : buf + 1;
    sb  = (sb  == 2) ? 0 : sb + 1;
  }

  // epilogue: C/D layout col=lane&15, row=(lane>>4)*4+reg (m89/m91 verified)
#pragma unroll
  for (int i = 0; i < 4; ++i) {
#pragma unroll
    for (int j = 0; j < JN; ++j) {
      const int col = n0 + wc * WCW + j * 16 + l15;
      const float bsv = bias[col];
#pragma unroll
      for (int r = 0; r < 4; ++r) {
        const int row = m0 + wr * 64 + i * 16 + l4 * 4 + r;
        const float v = acc[i][j][r] + bsv;
        if (mode == 3) {
          dout[(size_t)row * EMB + col] = v;
        } else {
          const int b = row >> 11, n = row & (SEQ - 1);
          const int h = col >> 6, d = col & (HD - 1);
          if (mode == 0)
            Qb[(((size_t)(b * NH + h)) * SEQ + n) * HD + d] = f2bf(v);
          else if (mode == 1)
            Kb[(((size_t)(b * NH + h)) * SEQ + n) * HD + d] = f2bf(v * LOG2E);
          else
            Vt[(((size_t)(b * NH + h)) * HD + d) * SEQ + n] = f2bf(v);
        }
      }
    }
  }
}

// ---------------- flash attention (r19: KV-split x2 for occupancy) ----------
// grid (512, 2): blockIdx.y = KV half (16 tiles each). 1024 blocks -> 3
// blocks/CU resident (LDS 144KB) = 12 waves/CU vs 8. The no-max softmax makes
// partial combine LINEAR: O = (a1+a2)/((l1+l2)*32) — no max rebasing. Partials
// written raw-bf16 to pA/pB (reusing dead xb/yb), l to lP (dead WtAll[0]).
// Else identical to r18: conflict-free full-rank swizzle, 3-buffer LDS, one
// barrier/iter, counted vmcnt(4), permlane P-pack, exp2-domain softmax.
#define KVB 64
#define NTH (SEQ/KVB/2)   // 16 tiles per half

__global__ __launch_bounds__(256, 3) void flash_kernel(
    const unsigned short* __restrict__ Qb,
    const unsigned short* __restrict__ Kb,
    const unsigned short* __restrict__ Vt,
    unsigned short* __restrict__ pA,
    unsigned short* __restrict__ pB,
    float* __restrict__ lP) {
  __shared__ __align__(16) char Ks[3][8192];   // [key][d] 64x64 bf16, swizzled
  __shared__ __align__(16) char Vs[3][8192];   // [d][key] 64x64 bf16, swizzled

  const int tid = threadIdx.x;                 // 0..255
  const int lane = tid & 63, wid = tid >> 6;   // 4 waves
  const int l31 = lane & 31, hi = lane >> 5;

  // XCD-aware decode: 512 x-blocks; XCD k (= lin%8) gets bh in [4k,4k+4)
  const int lin = blockIdx.x;
  const int half = blockIdx.y;                 // KV half
  const int swz = (lin & 7) * 64 + (lin >> 3);
  const int bh = swz >> 4;                     // 0..31
  const int qt = swz & 15;                     // 0..15
  const int bb = bh >> 4, hh = bh & 15;
  const int q0 = qt * 128 + wid * 32;

  const unsigned short* Qp = Qb + (size_t)bh * SEQ * HD;
  const unsigned short* Kp = Kb + (size_t)bh * SEQ * HD + (size_t)half * (SEQ / 2) * HD;
  const unsigned short* Vp = Vt + (size_t)bh * HD * SEQ + (size_t)half * (SEQ / 2);

  const int srow = tid >> 3;                   // 0..31 (row within half-tile)
  const int sslot = tid & 7;                   // 16B slot within 128B row

  // Q B-frags FIRST (oldest in vmcnt queue)
  bf16x8 qf[4];
#pragma unroll
  for (int kt = 0; kt < 4; ++kt)
    qf[kt] = *reinterpret_cast<const bf16x8*>(Qp + (size_t)(q0 + l31) * HD + kt * 16 + hi * 8);

  // stage: source col pre-swizzled with the FULL-RANK key (r&7)^((r>>3)&7)
#define SWZ(r) (((r) & 7) ^ (((r) >> 3) & 7))
#define STAGE(b, kv)                                                          \
  {                                                                           \
    _Pragma("unroll")                                                         \
    for (int it = 0; it < 2; ++it) {                                          \
      const int r = it * 32 + srow;                                           \
      async_load16(Kp + (size_t)((kv) + r) * HD + ((sslot ^ SWZ(r)) * 8),     \
                   Ks[b] + it * 4096 + tid * 16);                             \
      async_load16(Vp + (size_t)r * SEQ + (kv) + ((sslot ^ SWZ(r)) * 8),      \
                   Vs[b] + it * 4096 + tid * 16);                             \
    }                                                                         \
  }

  STAGE(0, 0)
  STAGE(1, KVB)

  f32x16 accO[2] = {};
  float lp[8] = {0.f, 0.f, 0.f, 0.f, 0.f, 0.f, 0.f, 0.f};  // per-lane l partials

  int buf = 0, sb = 2;
  for (int t = 0; t < NTH; ++t) {
    __builtin_amdgcn_sched_barrier(0);   // pin: iter-t reads can't sink below
    // stage(t) landed; stage(t+1)'s 4 loads stay in flight (counted vmcnt)
    if (t < NTH - 1) {
      asm volatile("s_waitcnt vmcnt(4)" ::: "memory");
    } else {
      asm volatile("s_waitcnt vmcnt(0)" ::: "memory");
    }
    __builtin_amdgcn_s_barrier();
    __builtin_amdgcn_sched_barrier(0);   // pin: no ds_read hoists above barrier

    // issue stage(t+2) immediately (full iteration to land)
    if (t + 2 < NTH) { STAGE(sb, (t + 2) * KVB) }

    // ---- QK^T from Ks[buf]: kf row=key=t2*32+l31, k-chunk d0=kt*2+hi ----
    bf16x8 kf[2][4];
#pragma unroll
    for (int t2 = 0; t2 < 2; ++t2)
#pragma unroll
      for (int kt = 0; kt < 4; ++kt) {
        const int key = t2 * 32 + l31;
        kf[t2][kt] = *reinterpret_cast<const bf16x8*>(
            Ks[buf] + key * 128 + (((kt * 2 + hi) ^ SWZ(key)) * 16));
      }
    f32x16 sc[2] = {};
#pragma unroll
    for (int t2 = 0; t2 < 2; ++t2)
#pragma unroll
      for (int kt = 0; kt < 4; ++kt)
        sc[t2] = __builtin_amdgcn_mfma_f32_32x32x16_bf16(kf[t2][kt], qf[kt], sc[t2], 0, 0, 0);

    // ---- no-max softmax: p = exp2(s) in place; accumulate l partials ----
#pragma unroll
    for (int t2 = 0; t2 < 2; ++t2)
#pragma unroll
      for (int r = 0; r < 16; ++r) {
        sc[t2][r] = fast_exp2(sc[t2][r]);
        lp[(t2 << 2) | (r & 3)] += sc[t2][r];
      }

    // ---- pack P into B-frags: cvt_pk + permlane32_swap (2 swaps/frag) ----
    bf16x8 pf[4];
#pragma unroll
    for (int kt = 0; kt < 4; ++kt) {
      const int t2 = kt >> 1, g = (kt & 1) * 8;
      unsigned int Aw = cvtpk_bf16(sc[t2][g + 0], sc[t2][g + 1]);  // keys 4hi+0,1
      unsigned int Cw = cvtpk_bf16(sc[t2][g + 2], sc[t2][g + 3]);  // keys 4hi+2,3
      unsigned int Bw = cvtpk_bf16(sc[t2][g + 4], sc[t2][g + 5]);  // keys 8+4hi+0,1
      unsigned int Dw = cvtpk_bf16(sc[t2][g + 6], sc[t2][g + 7]);  // keys 8+4hi+2,3
      swap32(Aw, Bw, hi);  // Aw=[A_lo,B_lo]=keys+0,1 ; Bw=[A_hi,B_hi]=keys+4,5
      swap32(Cw, Dw, hi);  // Cw=keys+2,3 ; Dw=keys+6,7
      union { unsigned int u[4]; bf16x8 v; } cvt;
      cvt.u[0] = Aw; cvt.u[1] = Cw; cvt.u[2] = Bw; cvt.u[3] = Dw;
      pf[kt] = cvt.v;
    }

    // ---- PV from Vs[buf]: vf row=d=dt*32+l31, k-chunk k0=kt*2+hi ----
    bf16x8 vf[2][4];
#pragma unroll
    for (int dt = 0; dt < 2; ++dt)
#pragma unroll
      for (int kt = 0; kt < 4; ++kt) {
        const int d = dt * 32 + l31;
        vf[dt][kt] = *reinterpret_cast<const bf16x8*>(
            Vs[buf] + d * 128 + (((kt * 2 + hi) ^ SWZ(d)) * 16));
      }
#pragma unroll
    for (int dt = 0; dt < 2; ++dt)
#pragma unroll
      for (int kt = 0; kt < 4; ++kt)
        accO[dt] = __builtin_amdgcn_mfma_f32_32x32x16_bf16(vf[dt][kt], pf[kt], accO[dt], 0, 0, 0);

    buf = (buf == 2) ? 0 : buf + 1;
    sb  = (sb  == 2) ? 0 : sb + 1;
  }
#undef STAGE
#undef SWZ

  // epilogue: write RAW partials (bf16 accO + f32 l); combine normalizes.
  const float ls = ((lp[0] + lp[1]) + (lp[2] + lp[3])) +
                   ((lp[4] + lp[5]) + (lp[6] + lp[7]));
  const float lI = xadd32(ls, hi);
  unsigned short* pOut = half ? pB : pA;
  if (hi == 0) lP[(size_t)half * 32 * SEQ + bh * SEQ + q0 + l31] = lI;
  const size_t obase = ((size_t)(bb * SEQ + q0 + l31)) * EMB + hh * HD;
#pragma unroll
  for (int dt = 0; dt < 2; ++dt)
#pragma unroll
    for (int rr = 0; rr < 4; ++rr) {
      ushort4 o;
      o.x = f2bf(accO[dt][rr * 4 + 0]);
      o.y = f2bf(accO[dt][rr * 4 + 1]);
      o.z = f2bf(accO[dt][rr * 4 + 2]);
      o.w = f2bf(accO[dt][rr * 4 + 3]);
      *reinterpret_cast<ushort4*>(pOut + obase + dt * 32 + 8 * rr + 4 * hi) = o;
    }
}

// ---------------- combine: attnb = (pA+pB) / ((l1+l2)*sqrt(E)) --------------
__global__ __launch_bounds__(256) void combine_kernel(
    const unsigned short* __restrict__ pA, const unsigned short* __restrict__ pB,
    const float* __restrict__ lP, unsigned short* __restrict__ attnb) {
  const int idx = blockIdx.x * 256 + threadIdx.x;   // 0..524287
  const int row = idx >> 7;          // 0..4095  (b*2048+n)
  const int c8  = idx & 127;         // 8-col group
  const int b = row >> 11, n = row & (SEQ - 1);
  const int h = c8 >> 3;
  const int bh = b * NH + h;
  const float l1 = lP[(size_t)bh * SEQ + n];
  const float l2 = lP[(size_t)32 * SEQ + (size_t)bh * SEQ + n];
  const float inv = 1.0f / ((l1 + l2) * 32.0f);
  const size_t off = (size_t)row * EMB + c8 * 8;
  union { ushort4 u4[2]; unsigned short u[8]; } a, c;
  a.u4[0] = *reinterpret_cast<const ushort4*>(pA + off);
  a.u4[1] = *reinterpret_cast<const ushort4*>(pA + off + 4);
  c.u4[0] = *reinterpret_cast<const ushort4*>(pB + off);
  c.u4[1] = *reinterpret_cast<const ushort4*>(pB + off + 4);
  union { ushort4 u4[2]; unsigned short u[8]; } o;
#pragma unroll
  for (int i = 0; i < 8; ++i)
    o.u[i] = f2bf((bf2f(a.u[i]) + bf2f(c.u[i])) * inv);
  *reinterpret_cast<ushort4*>(attnb + off) = o.u4[0];
  *reinterpret_cast<ushort4*>(attnb + off + 4) = o.u4[1];
}

extern "C" void kernel_launch(void* const* d_in, const int* in_sizes, int n_in,
                              void* d_out, int out_size, void* d_ws, size_t ws_size,
                              hipStream_t stream) {
  (void)in_sizes; (void)n_in; (void)out_size;
  const float* x  = (const float*)d_in[0];
  const float* y  = (const float*)d_in[1];
  const float* Wq = (const float*)d_in[2];
  const float* bq = (const float*)d_in[3];
  const float* Wk = (const float*)d_in[4];
  const float* bk = (const float*)d_in[5];
  const float* Wv = (const float*)d_in[6];
  const float* bv = (const float*)d_in[7];
  const float* Wo = (const float*)d_in[8];
  const float* bo = (const float*)d_in[9];
  float* out = (float*)d_out;

  char* ws = (char*)d_ws;
  unsigned short* xb    = (unsigned short*)(ws + (size_t)(0u  << 20));
  unsigned short* yb    = (unsigned short*)(ws + (size_t)(8u  << 20));
  unsigned short* WtAll = (unsigned short*)(ws + (size_t)(16u << 20));
  unsigned short* Qb    = (unsigned short*)(ws + (size_t)(24u << 20));
  unsigned short* Kb    = (unsigned short*)(ws + (size_t)(32u << 20));
  unsigned short* Vt    = (unsigned short*)(ws + (size_t)(40u << 20));
  unsigned short* attnb = (unsigned short*)(ws + (size_t)(48u << 20));
  // flash partials REUSE dead regions during/after flash:
  //   pA = xb region, pB = yb region (both dead after phase-0 GEMM)
  //   lP = WtAll[0] region (Wq^T dead after phase-0; phase-1 uses WtAll[3] at +6MB)
  unsigned short* pA = xb;
  unsigned short* pB = yb;
  float* lP = (float*)(ws + (size_t)(16u << 20));
  if (ws_size < ((size_t)56u << 20)) return;  // need 56 MB scratch

  // one merged prep launch: 8192 convert blocks + 1024 transpose blocks
  hipLaunchKernelGGL(prep_kernel, dim3(9216), dim3(256), 0, stream,
                     x, y, Wq, Wk, Wv, Wo, xb, yb, WtAll);
  hipLaunchKernelGGL((gemm_kernel<128>), dim3(EMB / BN, MROWS / 128, 3), dim3(256), 0, stream,
                     xb, yb, attnb, WtAll, bq, bk, bv, bo, Qb, Kb, Vt, out, 0);
  hipLaunchKernelGGL(flash_kernel, dim3(512, 2), dim3(256), 0, stream,
                     Qb, Kb, Vt, pA, pB, lP);
  hipLaunchKernelGGL(combine_kernel, dim3(2048), dim3(256), 0, stream,
                     pA, pB, lP, attnb);
  hipLaunchKernelGGL((gemm_kernel<64>), dim3(EMB / BN, MROWS / 64, 1), dim3(256), 0, stream,
                     xb, yb, attnb, WtAll, bq, bk, bv, bo, Qb, Kb, Vt, out, 1);
}

// Round 20
// 125.885 us; speedup vs baseline: 1.0828x; 1.0828x over previous
//
#include <hip/hip_runtime.h>
#include <stdint.h>

#define BATCH 2
#define SEQ   2048
#define EMB   1024
#define NH    16
#define HD    64
#define MROWS (BATCH*SEQ)   // 4096
#define LOG2E 1.4426950408889634f

using bf16x8 = __attribute__((ext_vector_type(8))) short;
using f32x4  = __attribute__((ext_vector_type(4))) float;
using f32x16 = __attribute__((ext_vector_type(16))) float;

__device__ __forceinline__ unsigned short f2bf(float f) {
  __bf16 b = (__bf16)f;                       // RNE fptrunc
  return __builtin_bit_cast(unsigned short, b);
}

__device__ __forceinline__ unsigned int cvtpk_bf16(float lo, float hi) {
  unsigned int w;
  asm("v_cvt_pk_bf16_f32 %0, %1, %2" : "=v"(w) : "v"(lo), "v"(hi));
  return w;
}

// 2^x in one v_exp_f32 (compiler-modeled). Inputs pre-scaled to exp2 domain.
#if __has_builtin(__builtin_amdgcn_exp2f)
__device__ __forceinline__ float fast_exp2(float x) { return __builtin_amdgcn_exp2f(x); }
#else
__device__ __forceinline__ float fast_exp2(float x) {
  float r;
  asm("v_exp_f32 %0, %1\n\ts_nop 1" : "=v"(r) : "v"(x));
  return r;
}
#endif

// cross-32 half exchange: a' = [a_lo, b_lo], b' = [a_hi, b_hi]. VALU.
__device__ __forceinline__ void swap32(unsigned int& a, unsigned int& b, int hi) {
#if __has_builtin(__builtin_amdgcn_permlane32_swap)
  (void)hi;
  typedef unsigned int u32x2_t __attribute__((ext_vector_type(2)));
  u32x2_t r = __builtin_amdgcn_permlane32_swap(a, b, false, false);
  a = r[0]; b = r[1];
#else
  const unsigned int ca = __shfl_xor(a, 32), cb = __shfl_xor(b, 32);
  const unsigned int na = hi ? cb : a;
  const unsigned int nb = hi ? b : ca;
  a = na; b = nb;
#endif
}

__device__ __forceinline__ float xadd32(float x, int hi) {
  unsigned int a = __builtin_bit_cast(unsigned int, x), b = a;
  swap32(a, b, hi);
  return __builtin_bit_cast(float, a) + __builtin_bit_cast(float, b);
}

__device__ __forceinline__ void async_load16(const void* g, void* l) {
  __builtin_amdgcn_global_load_lds(
      (__attribute__((address_space(1))) void*)g,
      (__attribute__((address_space(3))) void*)l,
      16, 0, 0);
}

// ---------------- merged prep: convert x, convert y, transpose weights ------
__global__ __launch_bounds__(256) void prep_kernel(
    const float* __restrict__ x, const float* __restrict__ y,
    const float* __restrict__ Wq, const float* __restrict__ Wk,
    const float* __restrict__ Wv, const float* __restrict__ Wo,
    unsigned short* __restrict__ xb, unsigned short* __restrict__ yb,
    unsigned short* __restrict__ WtAll) {
  __shared__ unsigned short tile[64][65];
  const int lin = blockIdx.x;
  if (lin < 8192) {
    const float* in = (lin < 4096) ? x : y;
    unsigned short* out = (lin < 4096) ? xb : yb;
    const int i = (lin & 4095) * 256 + threadIdx.x;   // < 1048576 float4s
    const float4 v = reinterpret_cast<const float4*>(in)[i];
    ushort4 o;
    o.x = f2bf(v.x); o.y = f2bf(v.y); o.z = f2bf(v.z); o.w = f2bf(v.w);
    reinterpret_cast<ushort4*>(out)[i] = o;
    return;   // convert blocks never reach the barrier below
  }
  const int tw = lin - 8192;
  const int z = tw >> 8;                      // 0..3
  const float* W = (z == 0) ? Wq : (z == 1) ? Wk : (z == 2) ? Wv : Wo;
  unsigned short* Wt = WtAll + (size_t)z * EMB * EMB;
  const int tc = threadIdx.x & 15;
  const int tr = threadIdx.x >> 4;
  const int n0 = ((tw >> 4) & 15) * 64, k0 = (tw & 15) * 64;
#pragma unroll
  for (int rr = 0; rr < 4; ++rr) {
    const int row = rr * 16 + tr;  // k-local
    float4 v = *reinterpret_cast<const float4*>(W + (size_t)(k0 + row) * EMB + n0 + tc * 4);
    tile[tc * 4 + 0][row] = f2bf(v.x);
    tile[tc * 4 + 1][row] = f2bf(v.y);
    tile[tc * 4 + 2][row] = f2bf(v.z);
    tile[tc * 4 + 3][row] = f2bf(v.w);
  }
  __syncthreads();
#pragma unroll
  for (int rr = 0; rr < 4; ++rr) {
    const int row = rr * 16 + tr;  // n-local
    ushort4 o;
    o.x = tile[row][tc * 4 + 0];
    o.y = tile[row][tc * 4 + 1];
    o.z = tile[row][tc * 4 + 2];
    o.w = tile[row][tc * 4 + 3];
    *reinterpret_cast<ushort4*>(Wt + (size_t)(n0 + row) * EMB + k0 + tc * 4) = o;
  }
}

// ---------------- GEMM: C[m][n] = A[m][:] . Wt[n][:] + bias[n] ----------------
// BMt x 128 tile, BK=32, 4 waves. 3-buffer LDS pipeline, counted vmcnt.
// T2 both-sides XOR swizzle (r16).
#define BN 128
#define BK 32
#define NKS (EMB/BK)   // 32

template <int BMt>
__global__ __launch_bounds__(256, 3) void gemm_kernel(
    const unsigned short* __restrict__ xb,
    const unsigned short* __restrict__ yb,
    const unsigned short* __restrict__ attnb,
    const unsigned short* __restrict__ WtAll,
    const float* __restrict__ bq, const float* __restrict__ bk,
    const float* __restrict__ bv, const float* __restrict__ bo,
    unsigned short* __restrict__ Qb, unsigned short* __restrict__ Kb,
    unsigned short* __restrict__ Vt, float* __restrict__ dout,
    int phase) {
  __shared__ __align__(16) unsigned short As[3][BMt * BK];
  __shared__ __align__(16) unsigned short Bs[3][BN * BK];

  const int z = blockIdx.z;
  const unsigned short* A;
  const unsigned short* Bt;
  const float* bias;
  int mode;
  if (phase == 0) {
    A    = (z == 0) ? xb : yb;
    Bt   = WtAll + (size_t)z * EMB * EMB;
    bias = (z == 0) ? bq : (z == 1) ? bk : bv;
    mode = z;                 // 0:Q 1:K(scaled by log2e) 2:V(transposed out)
  } else {
    A = attnb; Bt = WtAll + (size_t)3 * EMB * EMB; bias = bo; mode = 3;
  }

  const int tid = threadIdx.x;
  const int lane = tid & 63, wid = tid >> 6;
  constexpr int WC  = (BMt == 128) ? 2 : 4;    // wave cols
  constexpr int WCW = 128 / WC;                // cols per wave (64 or 32)
  constexpr int JN  = WCW / 16;                // j-blocks per wave (4 or 2)
  const int wr = (BMt == 128) ? (wid >> 1) : 0;
  const int wc = (BMt == 128) ? (wid & 1) : wid;
  const int l15 = lane & 15, l4 = lane >> 4;
  const int m0 = blockIdx.y * BMt, n0 = blockIdx.x * BN;

  const int crow = tid >> 2;   // 0..63
  const int cslot = tid & 3;
  const int ssw = cslot ^ ((crow >> 1) & 3);   // stage-side swizzled slot
  const int rsw = (l15 >> 1) & 3;              // read-side XOR key

  auto GSTAGE = [&](int b, int kt) {
    if constexpr (BMt == 128) {
#pragma unroll
      for (int it = 0; it < 2; ++it)
        async_load16(A + (size_t)(m0 + it * 64 + crow) * EMB + kt + ssw * 8,
                     (char*)As[b] + it * 4096 + wid * 1024);
    } else {
      async_load16(A + (size_t)(m0 + crow) * EMB + kt + ssw * 8,
                   (char*)As[b] + wid * 1024);
    }
#pragma unroll
    for (int it = 0; it < 2; ++it)
      async_load16(Bt + (size_t)(n0 + it * 64 + crow) * EMB + kt + ssw * 8,
                   (char*)Bs[b] + it * 4096 + wid * 1024);
  };

  GSTAGE(0, 0);
  GSTAGE(1, BK);

  f32x4 acc[4][JN] = {};

  int buf = 0, sb = 2;
  for (int s = 0; s < NKS; ++s) {
    __builtin_amdgcn_sched_barrier(0);
    if (s < NKS - 1) {
      if constexpr (BMt == 128) {
        asm volatile("s_waitcnt vmcnt(4)" ::: "memory");
      } else {
        asm volatile("s_waitcnt vmcnt(3)" ::: "memory");
      }
    } else {
      asm volatile("s_waitcnt vmcnt(0)" ::: "memory");
    }
    __builtin_amdgcn_s_barrier();
    __builtin_amdgcn_sched_barrier(0);

    if (s + 2 < NKS) { GSTAGE(sb, (s + 2) * BK); }

    bf16x8 af[4], bfr[JN];
#pragma unroll
    for (int i = 0; i < 4; ++i)
      af[i] = *reinterpret_cast<const bf16x8*>(
          (const char*)As[buf] + (wr * 64 + i * 16 + l15) * 64 + ((l4 ^ rsw) * 16));
#pragma unroll
    for (int j = 0; j < JN; ++j)
      bfr[j] = *reinterpret_cast<const bf16x8*>(
          (const char*)Bs[buf] + (wc * WCW + j * 16 + l15) * 64 + ((l4 ^ rsw) * 16));
#pragma unroll
    for (int i = 0; i < 4; ++i)
#pragma unroll
      for (int j = 0; j < JN; ++j)
        acc[i][j] = __builtin_amdgcn_mfma_f32_16x16x32_bf16(af[i], bfr[j], acc[i][j], 0, 0, 0);

    buf = (buf == 2) ? 0 : buf + 1;
    sb  = (sb  == 2) ? 0 : sb + 1;
  }

  // epilogue: C/D layout col=lane&15, row=(lane>>4)*4+reg (m89/m91 verified)
#pragma unroll
  for (int i = 0; i < 4; ++i) {
#pragma unroll
    for (int j = 0; j < JN; ++j) {
      const int col = n0 + wc * WCW + j * 16 + l15;
      const float bsv = bias[col];
#pragma unroll
      for (int r = 0; r < 4; ++r) {
        const int row = m0 + wr * 64 + i * 16 + l4 * 4 + r;
        const float v = acc[i][j][r] + bsv;
        if (mode == 3) {
          dout[(size_t)row * EMB + col] = v;
        } else {
          const int b = row >> 11, n = row & (SEQ - 1);
          const int h = col >> 6, d = col & (HD - 1);
          if (mode == 0)
            Qb[(((size_t)(b * NH + h)) * SEQ + n) * HD + d] = f2bf(v);
          else if (mode == 1)
            Kb[(((size_t)(b * NH + h)) * SEQ + n) * HD + d] = f2bf(v * LOG2E);
          else
            Vt[(((size_t)(b * NH + h)) * HD + d) * SEQ + n] = f2bf(v);
        }
      }
    }
  }
}

// ---------------- flash attention (r15/r16 best: no-max softmax, 50us) ------
// 4 waves x 32 q-rows (128 q/block), KVB=64, grid 512. Swapped QK^T
// (S^T = mfma(K,Q), 32x32x16). K/V staged via global_load_lds into
// TRIPLE-buffered XOR-swizzled LDS -> ONE barrier/iter, counted vmcnt(4).
// No-max softmax: p = exp2(s) directly (energies bounded; scale cancels in
// O = PV/l); per-lane l partials, single cross-lane reduce in epilogue.
#define KVB 64
#define NT  (SEQ/KVB)   // 32

__global__ __launch_bounds__(256, 2) void flash_kernel(
    const unsigned short* __restrict__ Qb,
    const unsigned short* __restrict__ Kb,
    const unsigned short* __restrict__ Vt,
    unsigned short* __restrict__ attnb) {
  __shared__ __align__(16) char Ks[3][8192];   // [key][d] 64x64 bf16, swizzled
  __shared__ __align__(16) char Vs[3][8192];   // [d][key] 64x64 bf16, swizzled

  const int tid = threadIdx.x;                 // 0..255
  const int lane = tid & 63, wid = tid >> 6;   // 4 waves
  const int l31 = lane & 31, hi = lane >> 5;

  // XCD-aware decode: grid=512; XCD k (= lin%8) gets bh in [4k,4k+4)
  const int lin = blockIdx.x;
  const int swz = (lin & 7) * 64 + (lin >> 3);
  const int bh = swz >> 4;                     // 0..31
  const int qt = swz & 15;                     // 0..15
  const int bb = bh >> 4, hh = bh & 15;
  const int q0 = qt * 128 + wid * 32;

  const unsigned short* Qp = Qb + (size_t)bh * SEQ * HD;
  const unsigned short* Kp = Kb + (size_t)bh * SEQ * HD;
  const unsigned short* Vp = Vt + (size_t)bh * HD * SEQ;

  const int srow = tid >> 3;                   // 0..31 (row within half-tile)
  const int sslot = tid & 7;                   // 16B slot within 128B row

  // Q B-frags FIRST (oldest in vmcnt queue)
  bf16x8 qf[4];
#pragma unroll
  for (int kt = 0; kt < 4; ++kt)
    qf[kt] = *reinterpret_cast<const bf16x8*>(Qp + (size_t)(q0 + l31) * HD + kt * 16 + hi * 8);

  // stage(tile kv -> buffer b): 4 loads/thread; source col pre-swizzled so
  // linear LDS (dest base + lane*16) + XOR'd read = bijective swizzle.
#define STAGE(b, kv)                                                        \
  {                                                                         \
    _Pragma("unroll")                                                       \
    for (int it = 0; it < 2; ++it) {                                        \
      const int r = it * 32 + srow;                                         \
      async_load16(Kp + (size_t)((kv) + r) * HD + ((sslot ^ (r & 7)) * 8),  \
                   Ks[b] + it * 4096 + tid * 16);                           \
      async_load16(Vp + (size_t)r * SEQ + (kv) + ((sslot ^ (r & 7)) * 8),   \
                   Vs[b] + it * 4096 + tid * 16);                           \
    }                                                                       \
  }

  STAGE(0, 0)
  STAGE(1, KVB)

  f32x16 accO[2] = {};
  float lp[8] = {0.f, 0.f, 0.f, 0.f, 0.f, 0.f, 0.f, 0.f};  // per-lane l partials

  int buf = 0, sb = 2;
  for (int t = 0; t < NT; ++t) {
    __builtin_amdgcn_sched_barrier(0);   // pin: iter-t reads can't sink below
    // stage(t) landed; stage(t+1)'s 4 loads stay in flight (counted vmcnt)
    if (t < NT - 1) {
      asm volatile("s_waitcnt vmcnt(4)" ::: "memory");
    } else {
      asm volatile("s_waitcnt vmcnt(0)" ::: "memory");
    }
    __builtin_amdgcn_s_barrier();
    __builtin_amdgcn_sched_barrier(0);   // pin: no ds_read hoists above barrier

    // issue stage(t+2) immediately (full iteration to land)
    if (t + 2 < NT) { STAGE(sb, (t + 2) * KVB) }

    // ---- QK^T from Ks[buf]: kf row=key=t2*32+l31, k-chunk d0=kt*2+hi ----
    bf16x8 kf[2][4];
#pragma unroll
    for (int t2 = 0; t2 < 2; ++t2)
#pragma unroll
      for (int kt = 0; kt < 4; ++kt) {
        const int key = t2 * 32 + l31;
        kf[t2][kt] = *reinterpret_cast<const bf16x8*>(
            Ks[buf] + key * 128 + (((kt * 2 + hi) ^ (key & 7)) * 16));
      }
    f32x16 sc[2] = {};
#pragma unroll
    for (int t2 = 0; t2 < 2; ++t2)
#pragma unroll
      for (int kt = 0; kt < 4; ++kt)
        sc[t2] = __builtin_amdgcn_mfma_f32_32x32x16_bf16(kf[t2][kt], qf[kt], sc[t2], 0, 0, 0);

    // ---- no-max softmax: p = exp2(s) in place; accumulate l partials ----
#pragma unroll
    for (int t2 = 0; t2 < 2; ++t2)
#pragma unroll
      for (int r = 0; r < 16; ++r) {
        sc[t2][r] = fast_exp2(sc[t2][r]);
        lp[(t2 << 2) | (r & 3)] += sc[t2][r];
      }

    // ---- pack P into B-frags: cvt_pk + permlane32_swap (2 swaps/frag) ----
    bf16x8 pf[4];
#pragma unroll
    for (int kt = 0; kt < 4; ++kt) {
      const int t2 = kt >> 1, g = (kt & 1) * 8;
      unsigned int Aw = cvtpk_bf16(sc[t2][g + 0], sc[t2][g + 1]);  // keys 4hi+0,1
      unsigned int Cw = cvtpk_bf16(sc[t2][g + 2], sc[t2][g + 3]);  // keys 4hi+2,3
      unsigned int Bw = cvtpk_bf16(sc[t2][g + 4], sc[t2][g + 5]);  // keys 8+4hi+0,1
      unsigned int Dw = cvtpk_bf16(sc[t2][g + 6], sc[t2][g + 7]);  // keys 8+4hi+2,3
      swap32(Aw, Bw, hi);  // Aw=[A_lo,B_lo]=keys+0,1 ; Bw=[A_hi,B_hi]=keys+4,5
      swap32(Cw, Dw, hi);  // Cw=keys+2,3 ; Dw=keys+6,7
      union { unsigned int u[4]; bf16x8 v; } cvt;
      cvt.u[0] = Aw; cvt.u[1] = Cw; cvt.u[2] = Bw; cvt.u[3] = Dw;
      pf[kt] = cvt.v;
    }

    // ---- PV from Vs[buf]: vf row=d=dt*32+l31, k-chunk k0=kt*2+hi ----
    bf16x8 vf[2][4];
#pragma unroll
    for (int dt = 0; dt < 2; ++dt)
#pragma unroll
      for (int kt = 0; kt < 4; ++kt) {
        const int d = dt * 32 + l31;
        vf[dt][kt] = *reinterpret_cast<const bf16x8*>(
            Vs[buf] + d * 128 + (((kt * 2 + hi) ^ (d & 7)) * 16));
      }
#pragma unroll
    for (int dt = 0; dt < 2; ++dt)
#pragma unroll
      for (int kt = 0; kt < 4; ++kt)
        accO[dt] = __builtin_amdgcn_mfma_f32_32x32x16_bf16(vf[dt][kt], pf[kt], accO[dt], 0, 0, 0);

    buf = (buf == 2) ? 0 : buf + 1;
    sb  = (sb  == 2) ? 0 : sb + 1;
  }
#undef STAGE

  // epilogue: single cross-lane l reduce, then O = accO / (l * sqrt(E))
  const float ls = ((lp[0] + lp[1]) + (lp[2] + lp[3])) +
                   ((lp[4] + lp[5]) + (lp[6] + lp[7]));
  const float lI = xadd32(ls, hi);
  const float inv = 1.0f / (lI * 32.0f);
  const size_t obase = ((size_t)(bb * SEQ + q0 + l31)) * EMB + hh * HD;
#pragma unroll
  for (int dt = 0; dt < 2; ++dt)
#pragma unroll
    for (int rr = 0; rr < 4; ++rr) {
      ushort4 o;
      o.x = f2bf(accO[dt][rr * 4 + 0] * inv);
      o.y = f2bf(accO[dt][rr * 4 + 1] * inv);
      o.z = f2bf(accO[dt][rr * 4 + 2] * inv);
      o.w = f2bf(accO[dt][rr * 4 + 3] * inv);
      *reinterpret_cast<ushort4*>(attnb + obase + dt * 32 + 8 * rr + 4 * hi) = o;
    }
}

extern "C" void kernel_launch(void* const* d_in, const int* in_sizes, int n_in,
                              void* d_out, int out_size, void* d_ws, size_t ws_size,
                              hipStream_t stream) {
  (void)in_sizes; (void)n_in; (void)out_size;
  const float* x  = (const float*)d_in[0];
  const float* y  = (const float*)d_in[1];
  const float* Wq = (const float*)d_in[2];
  const float* bq = (const float*)d_in[3];
  const float* Wk = (const float*)d_in[4];
  const float* bk = (const float*)d_in[5];
  const float* Wv = (const float*)d_in[6];
  const float* bv = (const float*)d_in[7];
  const float* Wo = (const float*)d_in[8];
  const float* bo = (const float*)d_in[9];
  float* out = (float*)d_out;

  char* ws = (char*)d_ws;
  unsigned short* xb    = (unsigned short*)(ws + (size_t)(0u  << 20));
  unsigned short* yb    = (unsigned short*)(ws + (size_t)(8u  << 20));
  unsigned short* WtAll = (unsigned short*)(ws + (size_t)(16u << 20));
  unsigned short* Qb    = (unsigned short*)(ws + (size_t)(24u << 20));
  unsigned short* Kb    = (unsigned short*)(ws + (size_t)(32u << 20));
  unsigned short* Vt    = (unsigned short*)(ws + (size_t)(40u << 20));
  unsigned short* attnb = (unsigned short*)(ws + (size_t)(48u << 20));
  if (ws_size < ((size_t)56u << 20)) return;  // need 56 MB scratch

  // one merged prep launch: 8192 convert blocks + 1024 transpose blocks
  hipLaunchKernelGGL(prep_kernel, dim3(9216), dim3(256), 0, stream,
                     x, y, Wq, Wk, Wv, Wo, xb, yb, WtAll);
  hipLaunchKernelGGL((gemm_kernel<128>), dim3(EMB / BN, MROWS / 128, 3), dim3(256), 0, stream,
                     xb, yb, attnb, WtAll, bq, bk, bv, bo, Qb, Kb, Vt, out, 0);
  hipLaunchKernelGGL(flash_kernel, dim3(SEQ / 128 * BATCH * NH), dim3(256), 0, stream,
                     Qb, Kb, Vt, attnb);
  hipLaunchKernelGGL((gemm_kernel<64>), dim3(EMB / BN, MROWS / 64, 1), dim3(256), 0, stream,
                     xb, yb, attnb, WtAll, bq, bk, bv, bo, Qb, Kb, Vt, out, 1);
}